// Round 1
// baseline (142.312 us; speedup 1.0000x reference)
//
#include <hip/hip_runtime.h>

#define NEG 5
#define MM 6          // morphemes per word
#define NCTX 6        // 1 + NEG
#define DD 128
#define WAVES_PER_BLOCK 4

__global__ __launch_bounds__(256) void sg_loss_kernel(
    const int*   __restrict__ data,           // [B, 12]
    const int*   __restrict__ word2morph,     // [B, 6]
    const float* __restrict__ word2morph_mask,// [B, 6]
    const int*   __restrict__ ctx2morph,      // [B, 6, 6]
    const float* __restrict__ ctx2morph_mask, // [B, 6, 6]
    const float* __restrict__ emb0,           // [V, 128]
    const float* __restrict__ emb1,           // [V, 128]
    float*       __restrict__ out,
    int B)
{
    const int lane = threadIdx.x & 63;
    const int wid  = threadIdx.x >> 6;
    const int b    = blockIdx.x * WAVES_PER_BLOCK + wid;

    float loss = 0.0f;

    if (b < B) {
        const int d0 = lane * 2;

        // ---- w = sum_m emb0[word2morph[b,m]] * mask[b,m]  (lane holds dims d0,d0+1)
        float wx = 0.0f, wy = 0.0f;
        #pragma unroll
        for (int m = 0; m < MM; ++m) {
            const int   idx = word2morph[b * MM + m];
            const float msk = word2morph_mask[b * MM + m];
            const float2 r = *reinterpret_cast<const float2*>(
                &emb0[(size_t)idx * DD + d0]);
            wx += r.x * msk;
            wy += r.y * msk;
        }

        // ---- 6 context embeddings (j=0 positive, j=1..5 negatives) + partial dots
        float p[NCTX];
        #pragma unroll
        for (int j = 0; j < NCTX; ++j) {
            float ex = 0.0f, ey = 0.0f;
            const int base = (b * NCTX + j) * MM;
            #pragma unroll
            for (int m = 0; m < MM; ++m) {
                const int   idx = ctx2morph[base + m];
                const float msk = ctx2morph_mask[base + m];
                const float2 r = *reinterpret_cast<const float2*>(
                    &emb1[(size_t)idx * DD + d0]);
                ex += r.x * msk;
                ey += r.y * msk;
            }
            p[j] = wx * ex + wy * ey;
        }

        // ---- wave-wide butterfly reduce of all 6 dots
        #pragma unroll
        for (int j = 0; j < NCTX; ++j) {
            float v = p[j];
            #pragma unroll
            for (int off = 32; off >= 1; off >>= 1)
                v += __shfl_xor(v, off, 64);
            p[j] = v;
        }

        if (lane == 0) {
            // pos: -log_sigmoid(clip(p0, -10, 10)) = log1p(exp(-x))
            float x = fminf(fmaxf(p[0], -10.0f), 10.0f);
            loss = log1pf(expf(-x));
            // neg: -log_sigmoid(clip(-pn, -10, 10)) * neg_mask
            #pragma unroll
            for (int n = 0; n < NEG; ++n) {
                float y = fminf(fmaxf(-p[1 + n], -10.0f), 10.0f);
                float msk = (float)data[b * (2 + 2 * NEG) + 2 + NEG + n];
                loss += log1pf(expf(-y)) * msk;
            }
        }
    }

    // ---- block reduce (lane0 of each wave holds its wave's loss)
    __shared__ float sacc[WAVES_PER_BLOCK];
    if (lane == 0) sacc[wid] = loss;
    __syncthreads();
    if (threadIdx.x == 0) {
        float s = 0.0f;
        #pragma unroll
        for (int w = 0; w < WAVES_PER_BLOCK; ++w) s += sacc[w];
        atomicAdd(out, s);
    }
}

extern "C" void kernel_launch(void* const* d_in, const int* in_sizes, int n_in,
                              void* d_out, int out_size, void* d_ws, size_t ws_size,
                              hipStream_t stream) {
    const int*   data     = (const int*)  d_in[0];
    const int*   w2m      = (const int*)  d_in[1];
    const float* w2m_mask = (const float*)d_in[2];
    const int*   c2m      = (const int*)  d_in[3];
    const float* c2m_mask = (const float*)d_in[4];
    const float* emb0     = (const float*)d_in[5];
    const float* emb1     = (const float*)d_in[6];
    float* out = (float*)d_out;

    const int B = in_sizes[1] / MM;   // word2morph has B*6 elements

    hipMemsetAsync(out, 0, sizeof(float), stream);

    const int blocks = (B + WAVES_PER_BLOCK - 1) / WAVES_PER_BLOCK;
    sg_loss_kernel<<<blocks, 64 * WAVES_PER_BLOCK, 0, stream>>>(
        data, w2m, w2m_mask, c2m, c2m_mask, emb0, emb1, out, B);
}

// Round 2
// 113.542 us; speedup vs baseline: 1.2534x; 1.2534x over previous
//
#include <hip/hip_runtime.h>

#define NEG 5
#define MM 6            // morphemes per word
#define NCTX 6          // 1 + NEG
#define DD 128
#define WPB 4           // waves per block
#define RPW 2           // rows per wave (one half-wave = one row)
#define RPB (WPB * RPW) // 8 rows per block
#define DROW 12         // data row stride = 2 + 2*NEG

__device__ __forceinline__ int geti(const int4& v, int c) {
    switch (c) { case 0: return v.x; case 1: return v.y; case 2: return v.z; default: return v.w; }
}
__device__ __forceinline__ float getf(const float4& v, int c) {
    switch (c) { case 0: return v.x; case 1: return v.y; case 2: return v.z; default: return v.w; }
}

__global__ __launch_bounds__(256, 4) void sg_loss_kernel(
    const int*   __restrict__ data,           // [B, 12]
    const int*   __restrict__ w2m,            // [B, 6]
    const float* __restrict__ w2m_mask,       // [B, 6]
    const int*   __restrict__ c2m,            // [B, 36]
    const float* __restrict__ c2m_mask,       // [B, 36]
    const float* __restrict__ emb0,           // [V, 128]
    const float* __restrict__ emb1,           // [V, 128]
    float*       __restrict__ out,
    int B)
{
    const int lane  = threadIdx.x & 63;
    const int wid   = threadIdx.x >> 6;
    const int sub   = lane >> 5;        // which half-wave (row within wave)
    const int slane = lane & 31;
    const int base  = lane & 32;        // shuffle base for this half-wave
    const int b     = blockIdx.x * RPB + wid * RPW + sub;

    float loss = 0.0f;

    if (b < B) {
        // ---------- lane-parallel prefetch of all indices/masks ----------
        int4   ci  = {0, 0, 0, 0};      // lanes 0..8  : ctx indices, 9 x int4
        float4 cmk = {0.f, 0.f, 0.f, 0.f}; // lanes 9..17 : ctx masks, 9 x float4
        int    wi  = 0;                 // lanes 18..23: word indices
        float  wmk = 0.f;               // lanes 24..29: word masks
        int    nm  = 0;                 // lanes 0..4  : negative-sample masks

        if (slane < 9) {
            ci  = reinterpret_cast<const int4*>(c2m + (size_t)b * (NCTX * MM))[slane];
        } else if (slane < 18) {
            cmk = reinterpret_cast<const float4*>(c2m_mask + (size_t)b * (NCTX * MM))[slane - 9];
        } else if (slane < 24) {
            wi  = w2m[(size_t)b * MM + (slane - 18)];
        } else if (slane < 30) {
            wmk = w2m_mask[(size_t)b * MM + (slane - 24)];
        }
        if (slane < NEG) nm = data[(size_t)b * DROW + 2 + NEG + slane];

        // broadcast neg masks to all lanes (must happen while wave converged)
        float nmf[NEG];
        #pragma unroll
        for (int n = 0; n < NEG; ++n)
            nmf[n] = (float)__shfl(nm, base + n, 64);

        const int d0 = slane * 4;       // this lane's 4 dims of the 128

        // ---------- word embedding bag: w = sum_m emb0[wi_m] * wmk_m ----------
        float4 w = {0.f, 0.f, 0.f, 0.f};
        {
            float4 rr[MM]; float mk[MM];
            #pragma unroll
            for (int m = 0; m < MM; ++m) {
                const int   idx = __shfl(wi, base + 18 + m, 64);
                mk[m]           = __shfl(wmk, base + 24 + m, 64);
                rr[m] = *reinterpret_cast<const float4*>(emb0 + (size_t)idx * DD + d0);
            }
            #pragma unroll
            for (int m = 0; m < MM; ++m) {
                w.x += rr[m].x * mk[m]; w.y += rr[m].y * mk[m];
                w.z += rr[m].z * mk[m]; w.w += rr[m].w * mk[m];
            }
        }

        // ---------- 6 context bags + partial dots ----------
        float p[NCTX];
        #pragma unroll
        for (int j = 0; j < NCTX; ++j) {
            float4 rr[MM]; float mk[MM];
            #pragma unroll
            for (int m = 0; m < MM; ++m) {
                const int flat = j * MM + m;
                const int k = flat >> 2, c = flat & 3;
                const int idx = __shfl(geti(ci, c), base + k, 64);
                mk[m]         = __shfl(getf(cmk, c), base + 9 + k, 64);
                rr[m] = *reinterpret_cast<const float4*>(emb1 + (size_t)idx * DD + d0);
            }
            float4 e = {0.f, 0.f, 0.f, 0.f};
            #pragma unroll
            for (int m = 0; m < MM; ++m) {
                e.x += rr[m].x * mk[m]; e.y += rr[m].y * mk[m];
                e.z += rr[m].z * mk[m]; e.w += rr[m].w * mk[m];
            }
            p[j] = w.x * e.x + w.y * e.y + w.z * e.z + w.w * e.w;
        }

        // ---------- per-half-wave (32-lane) butterfly reduction of 6 dots ----------
        #pragma unroll
        for (int j = 0; j < NCTX; ++j) {
            float v = p[j];
            #pragma unroll
            for (int off = 16; off >= 1; off >>= 1)
                v += __shfl_xor(v, off, 64);
            p[j] = v;
        }

        if (slane == 0) {
            float x = fminf(fmaxf(p[0], -10.0f), 10.0f);
            loss = log1pf(expf(-x));
            #pragma unroll
            for (int n = 0; n < NEG; ++n) {
                float y = fminf(fmaxf(-p[1 + n], -10.0f), 10.0f);
                loss += log1pf(expf(-y)) * nmf[n];
            }
        }
    }

    // ---------- block reduce: 8 partials -> 1 atomic ----------
    __shared__ float sacc[RPB];
    if (slane == 0) sacc[wid * RPW + sub] = loss;
    __syncthreads();
    if (threadIdx.x == 0) {
        float s = 0.0f;
        #pragma unroll
        for (int i = 0; i < RPB; ++i) s += sacc[i];
        atomicAdd(out, s);
    }
}

extern "C" void kernel_launch(void* const* d_in, const int* in_sizes, int n_in,
                              void* d_out, int out_size, void* d_ws, size_t ws_size,
                              hipStream_t stream) {
    const int*   data     = (const int*)  d_in[0];
    const int*   w2m      = (const int*)  d_in[1];
    const float* w2m_mask = (const float*)d_in[2];
    const int*   c2m      = (const int*)  d_in[3];
    const float* c2m_mask = (const float*)d_in[4];
    const float* emb0     = (const float*)d_in[5];
    const float* emb1     = (const float*)d_in[6];
    float* out = (float*)d_out;

    const int B = in_sizes[1] / MM;   // word2morph has B*6 elements

    hipMemsetAsync(out, 0, sizeof(float), stream);

    const int blocks = (B + RPB - 1) / RPB;
    sg_loss_kernel<<<blocks, 64 * WPB, 0, stream>>>(
        data, w2m, w2m_mask, c2m, c2m_mask, emb0, emb1, out, B);
}